// Round 1
// baseline (95.478 us; speedup 1.0000x reference)
//
#include <hip/hip_runtime.h>

// Problem constants (from setup_inputs): B=1024, C=16, M=4096, N=8192
constexpr int BB = 1024;
constexpr int CC = 16;
constexpr int MM = 4096;
constexpr int NN = 8192;

constexpr int BLOCK   = 256;  // threads per block, one output column n each
constexpr int B_CHUNK = 32;   // rows of b per block

#define LOG_2PI 1.8378770664093453f

__global__ __launch_bounds__(BLOCK) void gm_gather_kernel(
    const float* __restrict__ x,      // (B, C)
    const float* __restrict__ locs,   // (C, M)
    const float* __restrict__ scales, // (C, M)
    const int*   __restrict__ edges,  // (C, N)
    float* __restrict__ out)          // (B, N)
{
    const int n  = blockIdx.x * BLOCK + threadIdx.x;
    const int b0 = blockIdx.y * B_CHUNK;

    // Stage this block's x slice: x[b0 .. b0+B_CHUNK-1][0..C-1]  (512 f32, 2 KB)
    __shared__ float xs[B_CHUNK * CC];
    for (int i = threadIdx.x; i < B_CHUNK * CC; i += BLOCK) {
        xs[i] = x[b0 * CC + i];
    }
    __syncthreads();

    // Per-column coefficients: loc_c, 1/s_c in registers; constants pre-summed.
    float loc_r[CC];
    float inv_r[CC];
    float K = -0.5f * LOG_2PI * (float)CC;
#pragma unroll
    for (int c = 0; c < CC; ++c) {
        const int   e  = edges[c * NN + n];        // coalesced across lanes
        const float lc = locs[c * MM + e];         // gather, L2-resident (256 KB)
        const float s  = scales[c * MM + e] + 0.5f;
        loc_r[c] = lc;
        inv_r[c] = 1.0f / s;                       // s in [0.5, 1.5), safe
        K       -= __logf(s);
    }

    // Sweep b rows: acc = K - 0.5 * sum_c ((x - loc)/s)^2
    float* outp = out + (size_t)b0 * NN + n;
#pragma unroll 4
    for (int bb = 0; bb < B_CHUNK; ++bb) {
        float acc = K;
#pragma unroll
        for (int c = 0; c < CC; ++c) {
            const float d = (xs[bb * CC + c] - loc_r[c]) * inv_r[c];
            acc = fmaf(d * d, -0.5f, acc);
        }
        outp[(size_t)bb * NN] = acc;               // coalesced dword store
    }
}

extern "C" void kernel_launch(void* const* d_in, const int* in_sizes, int n_in,
                              void* d_out, int out_size, void* d_ws, size_t ws_size,
                              hipStream_t stream) {
    const float* x      = (const float*)d_in[0];
    const float* locs   = (const float*)d_in[1];
    const float* scales = (const float*)d_in[2];
    const int*   edges  = (const int*)d_in[3];
    float* out = (float*)d_out;

    dim3 grid(NN / BLOCK, BB / B_CHUNK);   // (32, 32) = 1024 blocks
    gm_gather_kernel<<<grid, dim3(BLOCK), 0, stream>>>(x, locs, scales, edges, out);
}

// Round 2
// 89.261 us; speedup vs baseline: 1.0697x; 1.0697x over previous
//
#include <hip/hip_runtime.h>

// Problem constants (from setup_inputs): B=1024, C=16, M=4096, N=8192
constexpr int BB = 1024;
constexpr int CC = 16;
constexpr int MM = 4096;
constexpr int NN = 8192;

constexpr int BLOCK   = 256;  // threads per block, one output column n each
constexpr int B_CHUNK = 32;   // rows of b per block (kernel B)

#define LOG_2PI 1.8378770664093453f

// ---------------- Kernel A: per-column coefficients (once, not 32x) --------
// ws layout (floats):
//   loc_w[c*NN + n]   : CC*NN
//   inv_w[c*NN + n]   : CC*NN
//   k_w[n]            : NN
__global__ __launch_bounds__(BLOCK) void coeff_kernel(
    const float* __restrict__ locs,   // (C, M)
    const float* __restrict__ scales, // (C, M)
    const int*   __restrict__ edges,  // (C, N)
    float* __restrict__ loc_w,
    float* __restrict__ inv_w,
    float* __restrict__ k_w)
{
    const int n = blockIdx.x * BLOCK + threadIdx.x;

    // Issue all edge loads first (independent), then the gathers.
    int e[CC];
#pragma unroll
    for (int c = 0; c < CC; ++c) e[c] = edges[c * NN + n];

    float K = -0.5f * LOG_2PI * (float)CC;
#pragma unroll
    for (int c = 0; c < CC; ++c) {
        const float lc = locs[c * MM + e[c]];
        const float s  = scales[c * MM + e[c]] + 0.5f;   // s in [0.5, 1.5)
        loc_w[c * NN + n] = lc;
        inv_w[c * NN + n] = 1.0f / s;
        K -= __logf(s);
    }
    k_w[n] = K;
}

// ---------------- Kernel B: pure streaming b-sweep -------------------------
__global__ __launch_bounds__(BLOCK) void stream_kernel(
    const float* __restrict__ x,      // (B, C)
    const float* __restrict__ loc_w,
    const float* __restrict__ inv_w,
    const float* __restrict__ k_w,
    float* __restrict__ out)          // (B, N)
{
    const int n  = blockIdx.x * BLOCK + threadIdx.x;
    const int b0 = blockIdx.y * B_CHUNK;

    // Stage x slice: 32 rows x 16 cols = 2 KB
    __shared__ float xs[B_CHUNK * CC];
    for (int i = threadIdx.x; i < B_CHUNK * CC; i += BLOCK) {
        xs[i] = x[b0 * CC + i];
    }
    __syncthreads();

    // Coalesced coefficient loads (no gathers, no logs here).
    float loc_r[CC];
    float inv_r[CC];
#pragma unroll
    for (int c = 0; c < CC; ++c) {
        loc_r[c] = loc_w[c * NN + n];
        inv_r[c] = inv_w[c * NN + n];
    }
    const float K = k_w[n];

    float* outp = out + (size_t)b0 * NN + n;
#pragma unroll 4
    for (int bb = 0; bb < B_CHUNK; ++bb) {
        float acc = K;
#pragma unroll
        for (int c = 0; c < CC; ++c) {
            const float d = (xs[bb * CC + c] - loc_r[c]) * inv_r[c];
            acc = fmaf(d * d, -0.5f, acc);
        }
        outp[(size_t)bb * NN] = acc;   // coalesced dword store per row
    }
}

extern "C" void kernel_launch(void* const* d_in, const int* in_sizes, int n_in,
                              void* d_out, int out_size, void* d_ws, size_t ws_size,
                              hipStream_t stream) {
    const float* x      = (const float*)d_in[0];
    const float* locs   = (const float*)d_in[1];
    const float* scales = (const float*)d_in[2];
    const int*   edges  = (const int*)d_in[3];
    float* out = (float*)d_out;

    float* loc_w = (float*)d_ws;                 // CC*NN floats
    float* inv_w = loc_w + (size_t)CC * NN;      // CC*NN floats
    float* k_w   = inv_w + (size_t)CC * NN;      // NN floats   (total ~1.1 MB)

    coeff_kernel<<<dim3(NN / BLOCK), dim3(BLOCK), 0, stream>>>(
        locs, scales, edges, loc_w, inv_w, k_w);

    stream_kernel<<<dim3(NN / BLOCK, BB / B_CHUNK), dim3(BLOCK), 0, stream>>>(
        x, loc_w, inv_w, k_w, out);
}